// Round 5
// baseline (716.599 us; speedup 1.0000x reference)
//
#include <hip/hip_runtime.h>

// Problem constants: B=N=256, D=S=1024
// out = [ctx 256*1024 fp32 ; W 256*256*1024 fp32]

typedef _Float16 half8 __attribute__((ext_vector_type(8)));
typedef _Float16 half4 __attribute__((ext_vector_type(4)));
typedef float floatx16 __attribute__((ext_vector_type(16)));

static __device__ __forceinline__ void split_f32(float x, _Float16& hi, _Float16& lo) {
    _Float16 h = (_Float16)x;
    hi = h;
    lo = (_Float16)(x - (float)h);
}

// ---------------------------------------------------------------------------
// Small GEMM body: C[M,N] = A[M,K] @ B, fp32 in, hi/lo fp16 split on BOTH
// operands (3 MFMAs). Tile 64x64, 256 threads, BK=32. (Shared by the
// standalone kernel and the combined gemm1+transpose kernel.)
// ---------------------------------------------------------------------------
template <bool BT, bool OUT_HILO>
__device__ __forceinline__ void gemm_body(
    const float* __restrict__ Ag, const float* __restrict__ Bg,
    float* __restrict__ Cf, _Float16* __restrict__ Chi, _Float16* __restrict__ Clo,
    int Kdim, int Ndim, int bx, int by)
{
    __shared__ __align__(16) _Float16 AsHi[4 * 64 * 8];
    __shared__ __align__(16) _Float16 AsLo[4 * 64 * 8];
    __shared__ __align__(16) _Float16 BsHi[4 * 64 * 8];
    __shared__ __align__(16) _Float16 BsLo[4 * 64 * 8];

    const int tid  = threadIdx.x;
    const int lane = tid & 63;
    const int wave = tid >> 6;
    const int wy = wave >> 1, wx = wave & 1;
    const int l31 = lane & 31, l5 = lane >> 5;
    const int m0 = by * 64, n0 = bx * 64;

    floatx16 acc;
#pragma unroll
    for (int j = 0; j < 16; ++j) acc[j] = 0.0f;

    const int sA_m  = tid >> 2;
    const int sA_kg = tid & 3;
    const int sB_n  = tid & 63;
    const int sB_kg = tid >> 6;

    const int nkt = Kdim / 32;
#pragma unroll 1
    for (int kt = 0; kt < nkt; ++kt) {
        __syncthreads();
        {
            const float* src = Ag + (size_t)(m0 + sA_m) * Kdim + kt * 32 + sA_kg * 8;
            half8 hi, lo;
#pragma unroll
            for (int j = 0; j < 8; ++j) {
                _Float16 h, l;
                split_f32(src[j], h, l);
                hi[j] = h; lo[j] = l;
            }
            *(half8*)&AsHi[(sA_kg * 64 + sA_m) * 8] = hi;
            *(half8*)&AsLo[(sA_kg * 64 + sA_m) * 8] = lo;
        }
        if constexpr (BT) {
            const float* src = Bg + (size_t)(n0 + sA_m) * Kdim + kt * 32 + sA_kg * 8;
            half8 hi, lo;
#pragma unroll
            for (int j = 0; j < 8; ++j) {
                _Float16 h, l;
                split_f32(src[j], h, l);
                hi[j] = h; lo[j] = l;
            }
            *(half8*)&BsHi[(sA_kg * 64 + sA_m) * 8] = hi;
            *(half8*)&BsLo[(sA_kg * 64 + sA_m) * 8] = lo;
        } else {
            const float* src = Bg + (size_t)(kt * 32 + sB_kg * 8) * Ndim + n0 + sB_n;
            half8 hi, lo;
#pragma unroll
            for (int j = 0; j < 8; ++j) {
                _Float16 h, l;
                split_f32(src[(size_t)j * Ndim], h, l);
                hi[j] = h; lo[j] = l;
            }
            *(half8*)&BsHi[(sB_kg * 64 + sB_n) * 8] = hi;
            *(half8*)&BsLo[(sB_kg * 64 + sB_n) * 8] = lo;
        }
        __syncthreads();
#pragma unroll
        for (int ks = 0; ks < 2; ++ks) {
            const int kg = ks * 2 + l5;
            const half8 ah = *(half8*)&AsHi[(kg * 64 + wy * 32 + l31) * 8];
            const half8 al = *(half8*)&AsLo[(kg * 64 + wy * 32 + l31) * 8];
            const half8 bh = *(half8*)&BsHi[(kg * 64 + wx * 32 + l31) * 8];
            const half8 bl = *(half8*)&BsLo[(kg * 64 + wx * 32 + l31) * 8];
            acc = __builtin_amdgcn_mfma_f32_32x32x16_f16(ah, bh, acc, 0, 0, 0);
            acc = __builtin_amdgcn_mfma_f32_32x32x16_f16(ah, bl, acc, 0, 0, 0);
            acc = __builtin_amdgcn_mfma_f32_32x32x16_f16(al, bh, acc, 0, 0, 0);
        }
    }

    // C/D layout (verified): col = lane&31, row = (reg&3) + 8*(reg>>2) + 4*(lane>>5)
#pragma unroll
    for (int reg = 0; reg < 16; ++reg) {
        const int row = m0 + wy * 32 + (reg & 3) + 8 * (reg >> 2) + 4 * l5;
        const int col = n0 + wx * 32 + l31;
        const float v = acc[reg];
        if constexpr (OUT_HILO) {
            _Float16 h, l;
            split_f32(v, h, l);
            Chi[(size_t)row * Ndim + col] = h;
            Clo[(size_t)row * Ndim + col] = l;
        } else {
            Cf[(size_t)row * Ndim + col] = v;
        }
    }
}

template <bool BT, bool OUT_HILO>
__global__ __launch_bounds__(256, 2) void gemm_small(
    const float* __restrict__ Ag, const float* __restrict__ Bg,
    float* __restrict__ Cf, _Float16* __restrict__ Chi, _Float16* __restrict__ Clo,
    int Kdim, int Ndim)
{
    gemm_body<BT, OUT_HILO>(Ag, Bg, Cf, Chi, Clo, Kdim, Ndim, blockIdx.x, blockIdx.y);
}

// ---------------------------------------------------------------------------
// Transpose body: FV16T[i][d][n] = fp16(FV[i][n][d]) for one (i, 64-d tile).
// Read coalesced float4 rows -> LDS (padded, 264 fp16 row stride = 528 B:
// 16-aligned for b128 reads, conflict-bounded writes) -> write coalesced
// b128 rows of FV16T.
// ---------------------------------------------------------------------------
__device__ __forceinline__ void transpose_body(
    const float* __restrict__ FV, _Float16* __restrict__ T, int i, int dt)
{
    __shared__ __align__(16) _Float16 tb[64 * 264];
    const int tid = threadIdx.x;
    const int dl = tid & 15;        // d-quad index (d = dl*4..+4)
    const int nq = tid >> 4;        // 0..15: n-quad index
    const float* src = FV + (size_t)i * 256 * 1024 + (size_t)dt * 64;

#pragma unroll
    for (int p = 0; p < 4; ++p) {
        const int n0 = p * 64 + nq * 4;
        float4 v[4];
#pragma unroll
        for (int r = 0; r < 4; ++r)
            v[r] = *(const float4*)(src + (size_t)(n0 + r) * 1024 + dl * 4);
#pragma unroll
        for (int q = 0; q < 4; ++q) {
            half4 h;
            h[0] = (_Float16)((&v[0].x)[q]);
            h[1] = (_Float16)((&v[1].x)[q]);
            h[2] = (_Float16)((&v[2].x)[q]);
            h[3] = (_Float16)((&v[3].x)[q]);
            *(half4*)&tb[(size_t)(dl * 4 + q) * 264 + n0] = h;
        }
    }
    __syncthreads();
    const int s = tid & 31, dg = tid >> 5;
#pragma unroll
    for (int q = 0; q < 8; ++q) {
        const int d = dg * 8 + q;
        const half8 h = *(half8*)&tb[(size_t)d * 264 + s * 8];
        *(half8*)(T + ((size_t)i * 1024 + dt * 64 + d) * 256 + s * 8) = h;
    }
}

// Combined: gemm1 (A1 = state @ Q^T, 64 blocks) + FV transpose (4096 blocks)
// run concurrently in one dispatch (gemm1 alone used only 25% of the CUs).
__global__ __launch_bounds__(256, 2) void gemm1_plus_transpose(
    const float* __restrict__ state, const float* __restrict__ Q,
    float* __restrict__ A1,
    const float* __restrict__ FV, _Float16* __restrict__ T)
{
    if (blockIdx.y < 4)
        gemm_body<true, false>(state, Q, A1, nullptr, nullptr, 1024, 1024,
                               blockIdx.x, blockIdx.y);
    else
        transpose_body(FV, T, blockIdx.y - 4, blockIdx.x);
}

// ---------------------------------------------------------------------------
// Lean fused kernel: B-fragments are single b128 loads from FV16T[i][d][n]
// (8 contiguous n at fixed d). Per chunk-pair per wave: 4 A-b128 + 16 B-b128
// + 32 MFMA (vs ~132 scattered dwords + 64 cvt before). Chunks processed in
// PAIRS so each 128 B FV16T line is consumed while L1/L2-hot. Epilogue FV
// values come from FV16T (L2-resident) as 4x b64 per tile; ctx in fp16 FV
// (error ~5e-3, well under tolerance). Geometry/swizzle identical to R3:
// 64 rows x 1024 d per block, 8 waves (2 wy x 4 wx), acc[8], 1024 blocks.
// ---------------------------------------------------------------------------
__global__ __launch_bounds__(512, 2) void fused_attn_t16(
    const _Float16* __restrict__ T, const _Float16* __restrict__ Mhi,
    const _Float16* __restrict__ Mlo, float* __restrict__ ctx,
    float* __restrict__ Wout)
{
    __shared__ __align__(16) float red1[64 * 4];
    __shared__ __align__(16) float red2[64 * 4];

    const int tid  = threadIdx.x;
    const int lane = tid & 63;
    const int wave = tid >> 6;
    const int wx = wave & 3;   // d-slice (256 cols)
    const int wy = wave >> 2;  // m-half (32 rows)
    const int l31 = lane & 31, l5 = lane >> 5;

    // XCD-aware swizzle (proven R1/R3 map): all 4 bt of an i on one XCD.
    const int w   = blockIdx.x;   // 0..1023
    const int xcd = w & 7;
    const int k   = w >> 3;       // 0..127
    const int i   = (xcd << 5) + (k >> 2);  // 0..255
    const int bt  = k & 3;                  // 0..3

    const _Float16* __restrict__ Ti = T + (size_t)i * 1024 * 256;

    floatx16 acc[8];
#pragma unroll
    for (int nt = 0; nt < 8; ++nt)
#pragma unroll
        for (int j = 0; j < 16; ++j) acc[nt][j] = 0.0f;

    // A-fragment: row (m) = bt*64 + wy*32 + l31, k = kt*16 + l5*8 + j
    const int arow = bt * 64 + wy * 32 + l31;
    const _Float16* __restrict__ Ah = Mhi + (size_t)arow * 256 + l5 * 8;
    const _Float16* __restrict__ Al = Mlo + (size_t)arow * 256 + l5 * 8;
    // B-fragment: B[k][col] = FV[i][n=k][d=col] = Ti[col*256 + k]
    const _Float16* __restrict__ Bb = Ti + ((size_t)(wx * 256 + l31)) * 256 + l5 * 8;

#pragma unroll 1
    for (int ktg = 0; ktg < 8; ++ktg) {   // chunk pairs: k = ktg*32 .. +32
        const half8 a0h = *(const half8*)(Ah + ktg * 32);
        const half8 a0l = *(const half8*)(Al + ktg * 32);
        const half8 a1h = *(const half8*)(Ah + ktg * 32 + 16);
        const half8 a1l = *(const half8*)(Al + ktg * 32 + 16);
        half8 b0[8], b1[8];
#pragma unroll
        for (int nt = 0; nt < 8; ++nt) {
            const _Float16* bp = Bb + (size_t)nt * 32 * 256 + ktg * 32;
            b0[nt] = *(const half8*)(bp);
            b1[nt] = *(const half8*)(bp + 16);
        }
#pragma unroll
        for (int nt = 0; nt < 8; ++nt) {
            acc[nt] = __builtin_amdgcn_mfma_f32_32x32x16_f16(a0h, b0[nt], acc[nt], 0, 0, 0);
            acc[nt] = __builtin_amdgcn_mfma_f32_32x32x16_f16(a0l, b0[nt], acc[nt], 0, 0, 0);
        }
#pragma unroll
        for (int nt = 0; nt < 8; ++nt) {
            acc[nt] = __builtin_amdgcn_mfma_f32_32x32x16_f16(a1h, b1[nt], acc[nt], 0, 0, 0);
            acc[nt] = __builtin_amdgcn_mfma_f32_32x32x16_f16(a1l, b1[nt], acc[nt], 0, 0, 0);
        }
    }

    // ---- softmax over d (rows span 4 wx waves) ----
    float st[16];
#pragma unroll
    for (int reg = 0; reg < 16; ++reg) {
        float v = acc[0][reg];
#pragma unroll
        for (int nt = 1; nt < 8; ++nt) v = fmaxf(v, acc[nt][reg]);
#pragma unroll
        for (int off = 1; off < 32; off <<= 1) v = fmaxf(v, __shfl_xor(v, off));
        st[reg] = v;
    }
    if (l31 == 0) {
#pragma unroll
        for (int reg = 0; reg < 16; ++reg) {
            const int row = wy * 32 + (reg & 3) + 8 * (reg >> 2) + 4 * l5;
            red1[row * 4 + wx] = st[reg];
        }
    }
    __syncthreads();
    float rmax[16];
#pragma unroll
    for (int reg = 0; reg < 16; ++reg) {
        const int row = wy * 32 + (reg & 3) + 8 * (reg >> 2) + 4 * l5;
        const float4 m4 = *(const float4*)&red1[row * 4];
        rmax[reg] = fmaxf(fmaxf(m4.x, m4.y), fmaxf(m4.z, m4.w));
    }
#pragma unroll
    for (int reg = 0; reg < 16; ++reg) {
        float s = 0.0f;
#pragma unroll
        for (int nt = 0; nt < 8; ++nt) {
            const float p = __expf(acc[nt][reg] - rmax[reg]);
            acc[nt][reg] = p;
            s += p;
        }
#pragma unroll
        for (int off = 1; off < 32; off <<= 1) s += __shfl_xor(s, off);
        st[reg] = s;
    }
    if (l31 == 0) {
#pragma unroll
        for (int reg = 0; reg < 16; ++reg) {
            const int row = wy * 32 + (reg & 3) + 8 * (reg >> 2) + 4 * l5;
            red2[row * 4 + wx] = st[reg];
        }
    }
    __syncthreads();
    float inv[16];
#pragma unroll
    for (int reg = 0; reg < 16; ++reg) {
        const int row = wy * 32 + (reg & 3) + 8 * (reg >> 2) + 4 * l5;
        const float4 s4 = *(const float4*)&red2[row * 4];
        inv[reg] = 1.0f / (s4.x + s4.y + s4.z + s4.w);
    }

    // ---- write W, accumulate context (FV from FV16T, b64 per row-quad) ----
    float csum[8];
#pragma unroll
    for (int nt = 0; nt < 8; ++nt) csum[nt] = 0.0f;

    const int rowbase = bt * 64 + wy * 32;
#pragma unroll
    for (int nt = 0; nt < 8; ++nt) {
        const int col = wx * 256 + nt * 32 + l31;
        const _Float16* fp = Ti + (size_t)col * 256 + rowbase + 4 * l5;
        half4 f[4];
#pragma unroll
        for (int g = 0; g < 4; ++g) f[g] = *(const half4*)(fp + 8 * g);
#pragma unroll
        for (int reg = 0; reg < 16; ++reg) {
            const int row = (reg & 3) + 8 * (reg >> 2) + 4 * l5;
            const float wv = acc[nt][reg] * inv[reg];
            Wout[((size_t)(i * 256 + rowbase + row)) * 1024 + col] = wv;
            csum[nt] += wv * (float)f[reg >> 2][reg & 3];
        }
    }
#pragma unroll
    for (int nt = 0; nt < 8; ++nt) {
        const float v = csum[nt] + __shfl_xor(csum[nt], 32);
        if (l5 == 0)
            atomicAdd(&ctx[(size_t)i * 1024 + wx * 256 + nt * 32 + l31], v);
    }
}

// ---------------------------------------------------------------------------
// Fallback fused kernel (R3, 283 us): used only if workspace can't hold FV16T.
// ---------------------------------------------------------------------------
__global__ __launch_bounds__(512, 2) void fused_attn(
    const float* __restrict__ FV, const _Float16* __restrict__ Mhi,
    const _Float16* __restrict__ Mlo, float* __restrict__ ctx,
    float* __restrict__ Wout)
{
    __shared__ __align__(16) float red1[64 * 4];
    __shared__ __align__(16) float red2[64 * 4];

    const int tid  = threadIdx.x;
    const int lane = tid & 63;
    const int wave = tid >> 6;
    const int wx = wave & 3;
    const int wy = wave >> 2;
    const int l31 = lane & 31, l5 = lane >> 5;

    const int w   = blockIdx.x;
    const int xcd = w & 7;
    const int k   = w >> 3;
    const int i   = (xcd << 5) + (k >> 2);
    const int bt  = k & 3;

    const float* __restrict__ FVi = FV + (size_t)i * 256 * 1024;

    floatx16 acc[8];
#pragma unroll
    for (int nt = 0; nt < 8; ++nt)
#pragma unroll
        for (int j = 0; j < 16; ++j) acc[nt][j] = 0.0f;

    const int arow = bt * 64 + wy * 32 + l31;
    const _Float16* __restrict__ Ah = Mhi + (size_t)arow * 256 + l5 * 8;
    const _Float16* __restrict__ Al = Mlo + (size_t)arow * 256 + l5 * 8;
    const float* __restrict__ Bbase = FVi + (size_t)(l5 * 8) * 1024 + wx * 256 + l31;

#pragma unroll 1
    for (int kt = 0; kt < 16; ++kt) {
        const half8 ah = *(const half8*)(Ah + kt * 16);
        const half8 al = *(const half8*)(Al + kt * 16);
        const float* bp = Bbase + (size_t)kt * 16 * 1024;
#pragma unroll
        for (int nt = 0; nt < 8; ++nt) {
            half8 b;
#pragma unroll
            for (int r = 0; r < 8; ++r)
                b[r] = (_Float16)bp[nt * 32 + (size_t)r * 1024];
            acc[nt] = __builtin_amdgcn_mfma_f32_32x32x16_f16(ah, b, acc[nt], 0, 0, 0);
            acc[nt] = __builtin_amdgcn_mfma_f32_32x32x16_f16(al, b, acc[nt], 0, 0, 0);
        }
    }

    float st[16];
#pragma unroll
    for (int reg = 0; reg < 16; ++reg) {
        float v = acc[0][reg];
#pragma unroll
        for (int nt = 1; nt < 8; ++nt) v = fmaxf(v, acc[nt][reg]);
#pragma unroll
        for (int off = 1; off < 32; off <<= 1) v = fmaxf(v, __shfl_xor(v, off));
        st[reg] = v;
    }
    if (l31 == 0) {
#pragma unroll
        for (int reg = 0; reg < 16; ++reg) {
            const int row = wy * 32 + (reg & 3) + 8 * (reg >> 2) + 4 * l5;
            red1[row * 4 + wx] = st[reg];
        }
    }
    __syncthreads();
    float rmax[16];
#pragma unroll
    for (int reg = 0; reg < 16; ++reg) {
        const int row = wy * 32 + (reg & 3) + 8 * (reg >> 2) + 4 * l5;
        const float4 m4 = *(const float4*)&red1[row * 4];
        rmax[reg] = fmaxf(fmaxf(m4.x, m4.y), fmaxf(m4.z, m4.w));
    }
#pragma unroll
    for (int reg = 0; reg < 16; ++reg) {
        float s = 0.0f;
#pragma unroll
        for (int nt = 0; nt < 8; ++nt) {
            const float p = __expf(acc[nt][reg] - rmax[reg]);
            acc[nt][reg] = p;
            s += p;
        }
#pragma unroll
        for (int off = 1; off < 32; off <<= 1) s += __shfl_xor(s, off);
        st[reg] = s;
    }
    if (l31 == 0) {
#pragma unroll
        for (int reg = 0; reg < 16; ++reg) {
            const int row = wy * 32 + (reg & 3) + 8 * (reg >> 2) + 4 * l5;
            red2[row * 4 + wx] = st[reg];
        }
    }
    __syncthreads();
    float inv[16];
#pragma unroll
    for (int reg = 0; reg < 16; ++reg) {
        const int row = wy * 32 + (reg & 3) + 8 * (reg >> 2) + 4 * l5;
        const float4 s4 = *(const float4*)&red2[row * 4];
        inv[reg] = 1.0f / (s4.x + s4.y + s4.z + s4.w);
    }

    float csum[8];
#pragma unroll
    for (int nt = 0; nt < 8; ++nt) csum[nt] = 0.0f;

    const int rowbase = bt * 64 + wy * 32;
#pragma unroll
    for (int nt = 0; nt < 8; ++nt) {
        const int col = wx * 256 + nt * 32 + l31;
#pragma unroll
        for (int reg = 0; reg < 16; ++reg) {
            const int row = (reg & 3) + 8 * (reg >> 2) + 4 * l5;
            const float wv = acc[nt][reg] * inv[reg];
            Wout[((size_t)(i * 256 + rowbase + row)) * 1024 + col] = wv;
            const float fv = FVi[(size_t)(rowbase + row) * 1024 + col];
            csum[nt] += wv * fv;
        }
    }
#pragma unroll
    for (int nt = 0; nt < 8; ++nt) {
        const float v = csum[nt] + __shfl_xor(csum[nt], 32);
        if (l5 == 0)
            atomicAdd(&ctx[(size_t)i * 1024 + wx * 256 + nt * 32 + l31], v);
    }
}

// ---------------------------------------------------------------------------
extern "C" void kernel_launch(void* const* d_in, const int* in_sizes, int n_in,
                              void* d_out, int out_size, void* d_ws, size_t ws_size,
                              hipStream_t stream)
{
    const float* FV    = (const float*)d_in[0];  // [256,256,1024]
    const float* state = (const float*)d_in[1];  // [256,1024]
    const float* Q     = (const float*)d_in[2];  // [1024,1024]
    const float* Km    = (const float*)d_in[3];  // [1024,256]

    float* out = (float*)d_out;
    float* ctx = out;                 // [256,1024]
    float* W   = out + 256 * 1024;    // [256,256,1024]

    char* ws = (char*)d_ws;
    float*    A1  = (float*)ws;                                 // [256,1024] fp32, 1 MB
    _Float16* Mhi = (_Float16*)(ws + (1 << 20));                // [256,256] f16, 128 KB
    _Float16* Mlo = (_Float16*)(ws + (1 << 20) + (1 << 17));    // [256,256] f16, 128 KB
    _Float16* T   = (_Float16*)(ws + (1 << 20) + (1 << 18));    // [256,1024,256] f16, 134 MB

    const size_t need = (size_t)(1 << 20) + (1 << 18) +
                        (size_t)256 * 1024 * 256 * sizeof(_Float16);

    (void)hipMemsetAsync(ctx, 0, 256 * 1024 * sizeof(float), stream);

    if (ws_size >= need) {
        // gemm1 (A1 = state @ Q^T) concurrent with FV16T transpose
        gemm1_plus_transpose<<<dim3(16, 260), 256, 0, stream>>>(state, Q, A1, FV, T);
        // M = A1 @ K -> hi/lo fp16
        gemm_small<false, true><<<dim3(4, 4), 256, 0, stream>>>(
            A1, Km, nullptr, Mhi, Mlo, 1024, 256);
        // lean fused: b128 B-loads from FV16T
        fused_attn_t16<<<dim3(1024), 512, 0, stream>>>(T, Mhi, Mlo, ctx, W);
    } else {
        gemm_small<true, false><<<dim3(16, 4), 256, 0, stream>>>(
            state, Q, A1, nullptr, nullptr, 1024, 1024);
        gemm_small<false, true><<<dim3(4, 4), 256, 0, stream>>>(
            A1, Km, nullptr, Mhi, Mlo, 1024, 256);
        fused_attn<<<dim3(1024), 512, 0, stream>>>(FV, Mhi, Mlo, ctx, W);
    }
}

// Round 6
// 592.045 us; speedup vs baseline: 1.2104x; 1.2104x over previous
//
#include <hip/hip_runtime.h>

// Problem constants: B=N=256, D=S=1024
// out = [ctx 256*1024 fp32 ; W 256*256*1024 fp32]

typedef _Float16 half8 __attribute__((ext_vector_type(8)));
typedef float floatx16 __attribute__((ext_vector_type(16)));

static __device__ __forceinline__ void split_f32(float x, _Float16& hi, _Float16& lo) {
    _Float16 h = (_Float16)x;
    hi = h;
    lo = (_Float16)(x - (float)h);
}

// ---------------------------------------------------------------------------
// Split-K small GEMM: C[M,N] += A[M,K-slice] @ B (fp32 atomicAdd epilogue).
// R0-R5 ran gemm1/gemm2 as 64/16-block dispatches -> 25%/6% machine occupancy,
// latency-bound, ~380 us combined (inferred: bench_total - fused = 380 us).
// Split-K fills the machine: grid (Ntiles, Mtiles, Ksplits), each block does
// KC/32 iterations and atomically accumulates its partial tile.
// fp32 in, hi/lo fp16 split on BOTH operands (3 MFMAs) for near-fp32 accuracy.
// BT=true: B stored [N,K] (contract fast dim). BT=false: B stored [K,N].
// Tile 64x64, 256 threads (4 waves as 2x2 of 32x32), BK=32.
// ---------------------------------------------------------------------------
template <bool BT>
__global__ __launch_bounds__(256, 2) void gemm_splitk(
    const float* __restrict__ Ag, const float* __restrict__ Bg,
    float* __restrict__ Cf, int Kdim, int Ndim, int KC)
{
    __shared__ __align__(16) _Float16 AsHi[4 * 64 * 8];
    __shared__ __align__(16) _Float16 AsLo[4 * 64 * 8];
    __shared__ __align__(16) _Float16 BsHi[4 * 64 * 8];
    __shared__ __align__(16) _Float16 BsLo[4 * 64 * 8];

    const int tid  = threadIdx.x;
    const int lane = tid & 63;
    const int wave = tid >> 6;
    const int wy = wave >> 1, wx = wave & 1;
    const int l31 = lane & 31, l5 = lane >> 5;
    const int m0 = blockIdx.y * 64, n0 = blockIdx.x * 64;
    const int kt0 = (blockIdx.z * KC) >> 5;   // first 32-chunk of this K-slice

    floatx16 acc;
#pragma unroll
    for (int j = 0; j < 16; ++j) acc[j] = 0.0f;

    const int sA_m  = tid >> 2;  // 0..63 (row for A / row-of-B for BT)
    const int sA_kg = tid & 3;   // 0..3
    const int sB_n  = tid & 63;  // NN staging: n (coalesced)
    const int sB_kg = tid >> 6;  // NN staging: kg

    const int nkt = KC / 32;
#pragma unroll 1
    for (int kt2 = 0; kt2 < nkt; ++kt2) {
        const int kt = kt0 + kt2;
        __syncthreads();
        {   // stage A chunk [32k x 64m] -> [kg][m][8] hi/lo
            const float* src = Ag + (size_t)(m0 + sA_m) * Kdim + kt * 32 + sA_kg * 8;
            half8 hi, lo;
#pragma unroll
            for (int j = 0; j < 8; ++j) {
                _Float16 h, l;
                split_f32(src[j], h, l);
                hi[j] = h; lo[j] = l;
            }
            *(half8*)&AsHi[(sA_kg * 64 + sA_m) * 8] = hi;
            *(half8*)&AsLo[(sA_kg * 64 + sA_m) * 8] = lo;
        }
        if constexpr (BT) {
            const float* src = Bg + (size_t)(n0 + sA_m) * Kdim + kt * 32 + sA_kg * 8;
            half8 hi, lo;
#pragma unroll
            for (int j = 0; j < 8; ++j) {
                _Float16 h, l;
                split_f32(src[j], h, l);
                hi[j] = h; lo[j] = l;
            }
            *(half8*)&BsHi[(sA_kg * 64 + sA_m) * 8] = hi;
            *(half8*)&BsLo[(sA_kg * 64 + sA_m) * 8] = lo;
        } else {
            const float* src = Bg + (size_t)(kt * 32 + sB_kg * 8) * Ndim + n0 + sB_n;
            half8 hi, lo;
#pragma unroll
            for (int j = 0; j < 8; ++j) {
                _Float16 h, l;
                split_f32(src[(size_t)j * Ndim], h, l);
                hi[j] = h; lo[j] = l;
            }
            *(half8*)&BsHi[(sB_kg * 64 + sB_n) * 8] = hi;
            *(half8*)&BsLo[(sB_kg * 64 + sB_n) * 8] = lo;
        }
        __syncthreads();
#pragma unroll
        for (int ks = 0; ks < 2; ++ks) {
            const int kg = ks * 2 + l5;
            const half8 ah = *(half8*)&AsHi[(kg * 64 + wy * 32 + l31) * 8];
            const half8 al = *(half8*)&AsLo[(kg * 64 + wy * 32 + l31) * 8];
            const half8 bh = *(half8*)&BsHi[(kg * 64 + wx * 32 + l31) * 8];
            const half8 bl = *(half8*)&BsLo[(kg * 64 + wx * 32 + l31) * 8];
            acc = __builtin_amdgcn_mfma_f32_32x32x16_f16(ah, bh, acc, 0, 0, 0);
            acc = __builtin_amdgcn_mfma_f32_32x32x16_f16(ah, bl, acc, 0, 0, 0);
            acc = __builtin_amdgcn_mfma_f32_32x32x16_f16(al, bh, acc, 0, 0, 0);
        }
    }

    // C/D layout (verified): col = lane&31, row = (reg&3) + 8*(reg>>2) + 4*(lane>>5)
#pragma unroll
    for (int reg = 0; reg < 16; ++reg) {
        const int row = m0 + wy * 32 + (reg & 3) + 8 * (reg >> 2) + 4 * l5;
        const int col = n0 + wx * 32 + l31;
        atomicAdd(&Cf[(size_t)row * Ndim + col], acc[reg]);
    }
}

// ---------------------------------------------------------------------------
// Fused (R1 structure, best measured 268 us): per (i, b-tile of 64):
// logits = M @ fp16(FV[i]) with in-register hi/lo split of fp32 M (2 MFMAs),
// row softmax over d=1024, write W, accumulate ctx[i,d] += W * FV[i,b,d].
// 512 threads = 8 waves (wy in {0,1} m-half, wx in {0..3} d-slice of 256).
// K=256 in 16 chunks of 16; register prefetch overlaps global load w/ compute.
// XCD-aware swizzle: all 4 bt-blocks of an i on one XCD (lockstep L2 sharing:
// proven FETCH ~= unique FV = 260 MB).
// ---------------------------------------------------------------------------
__global__ __launch_bounds__(512, 2) void fused_attn(
    const float* __restrict__ FV, const float* __restrict__ Mf,
    float* __restrict__ ctx, float* __restrict__ Wout)
{
    __shared__ __align__(16) _Float16 AsHi[2 * 64 * 8];
    __shared__ __align__(16) _Float16 AsLo[2 * 64 * 8];
    __shared__ __align__(16) _Float16 Bs[2 * 1024 * 8];
    __shared__ __align__(16) float red1[64 * 4];
    __shared__ __align__(16) float red2[64 * 4];

    const int tid  = threadIdx.x;
    const int lane = tid & 63;
    const int wave = tid >> 6;
    const int wx = wave & 3;   // d-slice (256 cols)
    const int wy = wave >> 2;  // m-half (32 rows)
    const int l31 = lane & 31, l5 = lane >> 5;

    // XCD-aware swizzle: all 4 bt of an i share one XCD.
    const int w   = blockIdx.x;   // 0..1023
    const int xcd = w & 7;
    const int k   = w >> 3;       // 0..127
    const int i   = (xcd << 5) + (k >> 2);  // 0..255
    const int bt  = k & 3;                  // 0..3

    const float* __restrict__ FVi = FV + (size_t)i * 256 * 1024;

    floatx16 acc[8];
#pragma unroll
    for (int nt = 0; nt < 8; ++nt)
#pragma unroll
        for (int j = 0; j < 16; ++j) acc[nt][j] = 0.0f;

    const int am = tid >> 1, akg = tid & 1;  // A staging (tid < 128)

    // ---- prefetch chunk 0 into registers ----
    float pv[4][8];
    float4 pa0, pa1;
#pragma unroll
    for (int rep = 0; rep < 4; ++rep) {
        const int q8 = rep >> 1;
        const int d  = (rep & 1) * 512 + tid;
        const float* src = FVi + (size_t)(q8 * 8) * 1024 + d;
#pragma unroll
        for (int r = 0; r < 8; ++r) pv[rep][r] = src[(size_t)r * 1024];
    }
    if (tid < 128) {
        const float* ap = Mf + (size_t)(bt * 64 + am) * 256 + akg * 8;
        pa0 = *(const float4*)(ap);
        pa1 = *(const float4*)(ap + 4);
    }

#pragma unroll 1
    for (int kt = 0; kt < 16; ++kt) {
        __syncthreads();  // drains prefetch (issued a full compute-phase ago)
        // ---- store staged chunk to LDS (fp32 M split to hi/lo here) ----
        if (tid < 128) {
            half8 hi, lo;
#pragma unroll
            for (int j = 0; j < 4; ++j) {
                _Float16 h, l;
                split_f32((&pa0.x)[j], h, l);
                hi[j] = h; lo[j] = l;
            }
#pragma unroll
            for (int j = 0; j < 4; ++j) {
                _Float16 h, l;
                split_f32((&pa1.x)[j], h, l);
                hi[4 + j] = h; lo[4 + j] = l;
            }
            *(half8*)&AsHi[(akg * 64 + am) * 8] = hi;
            *(half8*)&AsLo[(akg * 64 + am) * 8] = lo;
        }
#pragma unroll
        for (int rep = 0; rep < 4; ++rep) {
            const int q8 = rep >> 1;
            const int d  = (rep & 1) * 512 + tid;
            half8 h;
#pragma unroll
            for (int r = 0; r < 8; ++r) h[r] = (_Float16)pv[rep][r];
            *(half8*)&Bs[(q8 * 1024 + d) * 8] = h;
        }
        __syncthreads();
        // ---- prefetch next chunk (overlaps with compute below) ----
        if (kt + 1 < 16) {
#pragma unroll
            for (int rep = 0; rep < 4; ++rep) {
                const int q8 = rep >> 1;
                const int d  = (rep & 1) * 512 + tid;
                const float* src = FVi + (size_t)((kt + 1) * 16 + q8 * 8) * 1024 + d;
#pragma unroll
                for (int r = 0; r < 8; ++r) pv[rep][r] = src[(size_t)r * 1024];
            }
            if (tid < 128) {
                const float* ap = Mf + (size_t)(bt * 64 + am) * 256 + (kt + 1) * 16 + akg * 8;
                pa0 = *(const float4*)(ap);
                pa1 = *(const float4*)(ap + 4);
            }
        }
        // ---- compute: 8 n-tiles x (hi,lo) MFMA ----
        const half8 ah = *(half8*)&AsHi[(l5 * 64 + wy * 32 + l31) * 8];
        const half8 al = *(half8*)&AsLo[(l5 * 64 + wy * 32 + l31) * 8];
#pragma unroll
        for (int nt = 0; nt < 8; ++nt) {
            const half8 b = *(half8*)&Bs[(l5 * 1024 + wx * 256 + nt * 32 + l31) * 8];
            acc[nt] = __builtin_amdgcn_mfma_f32_32x32x16_f16(ah, b, acc[nt], 0, 0, 0);
            acc[nt] = __builtin_amdgcn_mfma_f32_32x32x16_f16(al, b, acc[nt], 0, 0, 0);
        }
    }

    // ---- softmax over d (rows span 4 wx waves) ----
    // lane holds: col = wx*256 + nt*32 + l31 ; row = wy*32 + (reg&3)+8*(reg>>2)+4*l5
    float st[16];
#pragma unroll
    for (int reg = 0; reg < 16; ++reg) {
        float v = acc[0][reg];
#pragma unroll
        for (int nt = 1; nt < 8; ++nt) v = fmaxf(v, acc[nt][reg]);
#pragma unroll
        for (int off = 1; off < 32; off <<= 1) v = fmaxf(v, __shfl_xor(v, off));
        st[reg] = v;
    }
    if (l31 == 0) {
#pragma unroll
        for (int reg = 0; reg < 16; ++reg) {
            const int row = wy * 32 + (reg & 3) + 8 * (reg >> 2) + 4 * l5;
            red1[row * 4 + wx] = st[reg];
        }
    }
    __syncthreads();
    float rmax[16];
#pragma unroll
    for (int reg = 0; reg < 16; ++reg) {
        const int row = wy * 32 + (reg & 3) + 8 * (reg >> 2) + 4 * l5;
        const float4 m4 = *(const float4*)&red1[row * 4];
        rmax[reg] = fmaxf(fmaxf(m4.x, m4.y), fmaxf(m4.z, m4.w));
    }
#pragma unroll
    for (int reg = 0; reg < 16; ++reg) {
        float s = 0.0f;
#pragma unroll
        for (int nt = 0; nt < 8; ++nt) {
            const float p = __expf(acc[nt][reg] - rmax[reg]);
            acc[nt][reg] = p;
            s += p;
        }
#pragma unroll
        for (int off = 1; off < 32; off <<= 1) s += __shfl_xor(s, off);
        st[reg] = s;
    }
    if (l31 == 0) {
#pragma unroll
        for (int reg = 0; reg < 16; ++reg) {
            const int row = wy * 32 + (reg & 3) + 8 * (reg >> 2) + 4 * l5;
            red2[row * 4 + wx] = st[reg];
        }
    }
    __syncthreads();
    float inv[16];
#pragma unroll
    for (int reg = 0; reg < 16; ++reg) {
        const int row = wy * 32 + (reg & 3) + 8 * (reg >> 2) + 4 * l5;
        const float4 s4 = *(const float4*)&red2[row * 4];
        inv[reg] = 1.0f / (s4.x + s4.y + s4.z + s4.w);
    }

    // ---- write W, accumulate context ----
    float csum[8];
#pragma unroll
    for (int nt = 0; nt < 8; ++nt) csum[nt] = 0.0f;

    const int rowbase = bt * 64 + wy * 32;
#pragma unroll
    for (int nt = 0; nt < 8; ++nt) {
        const int col = wx * 256 + nt * 32 + l31;
#pragma unroll
        for (int reg = 0; reg < 16; ++reg) {
            const int row = (reg & 3) + 8 * (reg >> 2) + 4 * l5;
            const float wv = acc[nt][reg] * inv[reg];
            Wout[((size_t)(i * 256 + rowbase + row)) * 1024 + col] = wv;
            const float fv = FVi[(size_t)(rowbase + row) * 1024 + col];
            csum[nt] += wv * fv;
        }
    }
#pragma unroll
    for (int nt = 0; nt < 8; ++nt) {
        const float v = csum[nt] + __shfl_xor(csum[nt], 32);
        if (l5 == 0)
            atomicAdd(&ctx[(size_t)i * 1024 + wx * 256 + nt * 32 + l31], v);
    }
}

// ---------------------------------------------------------------------------
extern "C" void kernel_launch(void* const* d_in, const int* in_sizes, int n_in,
                              void* d_out, int out_size, void* d_ws, size_t ws_size,
                              hipStream_t stream)
{
    const float* FV    = (const float*)d_in[0];  // [256,256,1024]
    const float* state = (const float*)d_in[1];  // [256,1024]
    const float* Q     = (const float*)d_in[2];  // [1024,1024]
    const float* Km    = (const float*)d_in[3];  // [1024,256]

    float* out = (float*)d_out;
    float* ctx = out;                 // [256,1024]
    float* W   = out + 256 * 1024;    // [256,256,1024]

    char* ws = (char*)d_ws;
    float* A1 = (float*)ws;               // [256,1024] fp32, 1 MB
    float* Mf = (float*)(ws + (1 << 20)); // [256,256]  fp32, 256 KB

    // split-K accumulators + ctx atomics -> zero them
    (void)hipMemsetAsync(ws, 0, (1 << 20) + (1 << 18), stream);
    (void)hipMemsetAsync(ctx, 0, 256 * 1024 * sizeof(float), stream);

    // A1 = state @ Q^T   (B stored [N,K]: Q[s,t], contract t)
    // split-K x8: 512 blocks (was 64) -> fills the machine
    gemm_splitk<true><<<dim3(16, 4, 8), 256, 0, stream>>>(
        state, Q, A1, 1024, 1024, 128);

    // M = A1 @ K  (B stored [K,N]) -> fp32 with split-K x16: 256 blocks (was 16)
    gemm_splitk<false><<<dim3(4, 4, 16), 256, 0, stream>>>(
        A1, Km, Mf, 1024, 256, 64);

    // fused logits -> softmax -> W + ctx (R1 structure, in-kernel hi/lo split)
    fused_attn<<<dim3(1024), 512, 0, stream>>>(FV, Mf, ctx, W);
}